// Round 8
// baseline (5660.888 us; speedup 1.0000x reference)
//
#include <hip/hip_runtime.h>

#define T_LEN 1024
#define HID   128
#define G4    512
#define NG2   256      // WGs for wide kernel (BCH=2)
#define NG    128      // fallback WGs
#define BCH   4        // fallback batch/WG
#define HB_STR 136     // halves per batch-col row

typedef _Float16 h2_t   __attribute__((ext_vector_type(2)));
typedef _Float16 f16x8  __attribute__((ext_vector_type(8)));
typedef float    f32x4n __attribute__((ext_vector_type(4)));

__device__ __forceinline__ float fsig(float v) {
  return __builtin_amdgcn_rcpf(1.0f + __expf(-v));
}
__device__ __forceinline__ float ftanh(float v) {
  float a = fabsf(v);
  float e = __expf(-2.0f * a);
  float t = (1.0f - e) * __builtin_amdgcn_rcpf(1.0f + e);
  return copysignf(t, v);
}

#define MFMA16(A, B, C) __builtin_amdgcn_mfma_f32_16x16x32_f16( \
    __builtin_bit_cast(f16x8, (A)), (B), (C), 0, 0, 0)

// ---------------------------------------------------------------------------
// Pack fp32 weights into per-wave A-fragment tiles for the 16-wave kernel.
// Wave w owns row-tiles {2w, 2w+1} of each matrix. Frag (w, s, kt):
//   s: 0,1 = Whh1 tiles 2w,2w+1; 2,3 = Whh2; 4,5 = Wih2.
//   row = 32w + 16*(s%2) + (l&15); k = 32*kt + (l>>4)*8 .. +8
// dst[(w*24 + s*4 + kt)*64 + l], total 384 frags * 64 lanes = 384 KB.
// ---------------------------------------------------------------------------
__global__ void __launch_bounds__(256) pack_frag3(
    const float* __restrict__ wa,   // Whh1
    const float* __restrict__ wb,   // Whh2
    const float* __restrict__ wc,   // Wih2
    uint4* __restrict__ dst) {
  int idx = blockIdx.x * 256 + threadIdx.x;   // 0..24575
  int l  = idx & 63;
  int f  = idx >> 6;        // 0..383
  int w  = f / 24;
  int rm = f % 24;
  int s  = rm >> 2;
  int kt = rm & 3;
  const float* src = (s < 2) ? wa : (s < 4) ? wb : wc;
  int row = 32 * w + 16 * (s & 1) + (l & 15);
  int k0  = 32 * kt + (l >> 4) * 8;
  const float* sp = src + (size_t)row * HID + k0;
  unsigned int r[4];
#pragma unroll
  for (int q = 0; q < 4; ++q) {
    h2_t h;
    h.x = (_Float16)sp[2 * q];
    h.y = (_Float16)sp[2 * q + 1];
    r[q] = __builtin_bit_cast(unsigned int, h);
  }
  dst[idx] = make_uint4(r[0], r[1], r[2], r[3]);
}

// ---------------------------------------------------------------------------
// Wide kernel: 256 WGs x 1024 threads (16 waves, 4 waves/SIMD), 2 batches/WG.
// Wave w: row-tiles {2w,2w+1} of Whh1 (C1a/C1b), Whh2+Wih2 (C2a/C2b shared
// accumulators). 24 frags = 96 AGPR/wave. Act role: tid -> (u=tid>>3,
// b=(tid>>2)&1, g=tid&3); 4-lane cluster holds i,f,g,o of one (u,b);
// combine via shfl_xor{1,2,3}; lane g==0 owns c and h.
// Schedule (3 barriers): A: MFMA{C1=Whh1*h1, C2+=Wih2*h1}, scatter C2.
// B: state-2 + out-partial, scatter C1, commit x. CD: out store,
// C2=Whh2*h2 (carry), state-1 -> h1(t+1).
// ---------------------------------------------------------------------------
__global__ void __launch_bounds__(1024, 4) lstm_wide(
    const float* __restrict__ xin, const float* __restrict__ Wih1,
    const float* __restrict__ bih1, const float* __restrict__ bhh1,
    const uint4* __restrict__ wfrag,
    const float* __restrict__ bih2, const float* __restrict__ bhh2,
    const float* __restrict__ Wout, const float* __restrict__ bout,
    float* __restrict__ outp)
{
  __shared__ _Float16 hB1[16 * HB_STR];
  __shared__ _Float16 hB2[16 * HB_STR];
  __shared__ float    g1b[HID * 8];   // [u][g][b] word = u*8+g*2+b
  __shared__ float    g2b[HID * 8];
  __shared__ float    prt[16][2];
  __shared__ float    xb[2];

  const int tid = threadIdx.x;
  const int l   = tid & 63;
  const int w   = tid >> 6;        // wave 0..15
  const int col = l & 15;
  const int q   = l >> 4;
  const int b0  = blockIdx.x * 2;
  const int g   = tid & 3;         // gate: 0:i 1:f 2:g 3:o
  const int b   = (tid >> 2) & 1;  // batch
  const int u   = tid >> 3;        // unit 0..127

  // ---- A-fragments (one-time) ----
  f32x4n W1a[4], W1b[4], W2a[4], W2b[4], WIa[4], WIb[4];
  {
    const uint4* wp = wfrag + (size_t)w * 24 * 64 + l;
#pragma unroll
    for (int kt = 0; kt < 4; ++kt) {
      W1a[kt] = __builtin_bit_cast(f32x4n, wp[(0 * 4 + kt) * 64]);
      W1b[kt] = __builtin_bit_cast(f32x4n, wp[(1 * 4 + kt) * 64]);
      W2a[kt] = __builtin_bit_cast(f32x4n, wp[(2 * 4 + kt) * 64]);
      W2b[kt] = __builtin_bit_cast(f32x4n, wp[(3 * 4 + kt) * 64]);
      WIa[kt] = __builtin_bit_cast(f32x4n, wp[(4 * 4 + kt) * 64]);
      WIb[kt] = __builtin_bit_cast(f32x4n, wp[(5 * 4 + kt) * 64]);
    }
#pragma unroll
    for (int kt = 0; kt < 4; ++kt)
      asm volatile("" : "+v"(W1a[kt]), "+v"(W1b[kt]), "+v"(W2a[kt]),
                        "+v"(W2b[kt]), "+v"(WIa[kt]), "+v"(WIb[kt]));
  }

  // ---- per-lane constants (role (u,b,g)) ----
  const float b1c = bih1[g * HID + u] + bhh1[g * HID + u];
  const float w1c = Wih1[g * HID + u];
  const float b2c = bih2[g * HID + u] + bhh2[g * HID + u];
  const float wou = Wout[u];
  const float bo  = bout[0];
  float c1 = 0.f, c2 = 0.f;

  // ---- zero h buffers; load x(0) ----
  {
    unsigned int* z1 = (unsigned int*)hB1;
    unsigned int* z2 = (unsigned int*)hB2;
    for (int i = tid; i < 16 * HB_STR / 2; i += 1024) { z1[i] = 0u; z2[i] = 0u; }
    if (tid < 2) xb[tid] = xin[(size_t)(b0 + tid) * T_LEN];
  }
  __syncthreads();

  // ---- prologue: h1(0) = layer1(x(0), h=0, c=0) ----
  {
    float xv = xb[b];
    float v  = fmaf(w1c, xv, b1c);
    float av = (g == 2) ? ftanh(v) : fsig(v);
    float tg = __shfl_xor(av, 2, 64);
    float so = __shfl_xor(av, 3, 64);
    float cn = av * tg;              // i*g (f*c0 = 0)
    float h1v = so * ftanh(cn);
    if (g == 0) {
      c1 = cn;
      hB1[b * HB_STR + u] = (_Float16)h1v;
    }
  }
  __syncthreads();

  const int boff = col * HB_STR + q * 8;
  f32x4n C2a = {0,0,0,0}, C2b = {0,0,0,0};

  for (int t = 0; t < T_LEN; ++t) {
    // ================= A: MFMA on h1(t) =================
    float xl = 0.f;
    if (tid < 2 && (t + 1) < T_LEN)
      xl = xin[(size_t)(b0 + tid) * T_LEN + (t + 1)];

    f16x8 Bh0 = *reinterpret_cast<const f16x8*>(&hB1[boff +  0]);
    f16x8 Bh1 = *reinterpret_cast<const f16x8*>(&hB1[boff + 32]);
    f16x8 Bh2 = *reinterpret_cast<const f16x8*>(&hB1[boff + 64]);
    f16x8 Bh3 = *reinterpret_cast<const f16x8*>(&hB1[boff + 96]);

    f32x4n C1a = {0,0,0,0}, C1b = {0,0,0,0};
    C1a = MFMA16(W1a[0], Bh0, C1a); C1a = MFMA16(W1a[1], Bh1, C1a);
    C1a = MFMA16(W1a[2], Bh2, C1a); C1a = MFMA16(W1a[3], Bh3, C1a);
    C1b = MFMA16(W1b[0], Bh0, C1b); C1b = MFMA16(W1b[1], Bh1, C1b);
    C1b = MFMA16(W1b[2], Bh2, C1b); C1b = MFMA16(W1b[3], Bh3, C1b);
    C2a = MFMA16(WIa[0], Bh0, C2a); C2a = MFMA16(WIa[1], Bh1, C2a);
    C2a = MFMA16(WIa[2], Bh2, C2a); C2a = MFMA16(WIa[3], Bh3, C2a);
    C2b = MFMA16(WIb[0], Bh0, C2b); C2b = MFMA16(WIb[1], Bh1, C2b);
    C2b = MFMA16(WIb[2], Bh2, C2b); C2b = MFMA16(WIb[3], Bh3, C2b);

    if (col < 2) {
#pragma unroll
      for (int i = 0; i < 4; ++i) {
        int R = 32 * w + 4 * q + i;
        g2b[(R & 127) * 8 + (R >> 7) * 2 + col] = C2a[i];
        int S = R + 16;
        g2b[(S & 127) * 8 + (S >> 7) * 2 + col] = C2b[i];
      }
    }
    __syncthreads();   // ---- barrier 1 ----

    // ================= B: state-2 + out partial =================
    {
      float v  = g2b[u * 8 + g * 2 + b] + b2c;
      float av = (g == 2) ? ftanh(v) : fsig(v);
      float sf = __shfl_xor(av, 1, 64);
      float tg = __shfl_xor(av, 2, 64);
      float so = __shfl_xor(av, 3, 64);
      float cn = fmaf(sf, c2, av * tg);   // valid at g==0 (av = si)
      float h2v = so * ftanh(cn);
      float po = 0.f;
      if (g == 0) {
        c2 = cn;
        hB2[b * HB_STR + u] = (_Float16)h2v;
        po = wou * h2v;
      }
      po += __shfl_xor(po, 8, 64);
      po += __shfl_xor(po, 16, 64);
      po += __shfl_xor(po, 32, 64);
      if (l == 0) prt[w][0] = po;
      if (l == 4) prt[w][1] = po;
    }
    if (col < 2) {
#pragma unroll
      for (int i = 0; i < 4; ++i) {
        int R = 32 * w + 4 * q + i;
        g1b[(R & 127) * 8 + (R >> 7) * 2 + col] = C1a[i];
        int S = R + 16;
        g1b[(S & 127) * 8 + (S >> 7) * 2 + col] = C1b[i];
      }
    }
    if (tid < 2) xb[tid] = xl;
    __syncthreads();   // ---- barrier 2 ----

    // ================= CD: out store + carry MFMA + state-1 =================
    if (tid < 2) {
      float s = 0.f;
#pragma unroll
      for (int ww = 0; ww < 16; ++ww) s += prt[ww][tid];
      outp[(size_t)(b0 + tid) * T_LEN + t] = s + bo;
    }

    f16x8 Dh0 = *reinterpret_cast<const f16x8*>(&hB2[boff +  0]);
    f16x8 Dh1 = *reinterpret_cast<const f16x8*>(&hB2[boff + 32]);
    f16x8 Dh2 = *reinterpret_cast<const f16x8*>(&hB2[boff + 64]);
    f16x8 Dh3 = *reinterpret_cast<const f16x8*>(&hB2[boff + 96]);

    C2a = (f32x4n){0,0,0,0};
    C2b = (f32x4n){0,0,0,0};
    C2a = MFMA16(W2a[0], Dh0, C2a); C2a = MFMA16(W2a[1], Dh1, C2a);
    C2a = MFMA16(W2a[2], Dh2, C2a); C2a = MFMA16(W2a[3], Dh3, C2a);
    C2b = MFMA16(W2b[0], Dh0, C2b); C2b = MFMA16(W2b[1], Dh1, C2b);
    C2b = MFMA16(W2b[2], Dh2, C2b); C2b = MFMA16(W2b[3], Dh3, C2b);

    {
      float xv = xb[b];
      float v  = g1b[u * 8 + g * 2 + b] + fmaf(w1c, xv, b1c);
      float av = (g == 2) ? ftanh(v) : fsig(v);
      float sf = __shfl_xor(av, 1, 64);
      float tg = __shfl_xor(av, 2, 64);
      float so = __shfl_xor(av, 3, 64);
      float cn = fmaf(sf, c1, av * tg);
      float h1v = so * ftanh(cn);
      if (g == 0) {
        c1 = cn;
        hB1[b * HB_STR + u] = (_Float16)h1v;
      }
    }
    __syncthreads();   // ---- barrier 3 ----
  }
}

// ---------------------------------------------------------------------------
// Fallback (round-1, known-correct fp32 path)
// ---------------------------------------------------------------------------
__global__ void __launch_bounds__(512) transpose_w(
    const float* __restrict__ w1, const float* __restrict__ w2,
    const float* __restrict__ w3, float* __restrict__ o) {
  int m = blockIdx.y;
  const float* src = (m == 0) ? w1 : (m == 1) ? w2 : w3;
  float* dst = o + (size_t)m * G4 * HID;
  int idx = blockIdx.x * 512 + threadIdx.x;
  int j = idx >> 7;
  int k = idx & (HID - 1);
  dst[k * G4 + j] = src[idx];
}

__device__ __forceinline__ float gact(float v, int gt) {
  return (gt == 2) ? ftanh(v) : fsig(v);
}

__device__ __forceinline__ void store_out4(const float4* h2buf, float wo0, float wo1,
                                           float bo, int tid, int b0,
                                           float* __restrict__ outp, int t) {
  float4 ha = h2buf[tid];
  float4 hb = h2buf[tid + 64];
  float p0 = wo0 * ha.x + wo1 * hb.x;
  float p1 = wo0 * ha.y + wo1 * hb.y;
  float p2 = wo0 * ha.z + wo1 * hb.z;
  float p3 = wo0 * ha.w + wo1 * hb.w;
#pragma unroll
  for (int off = 1; off < 64; off <<= 1) {
    p0 += __shfl_xor(p0, off, 64);
    p1 += __shfl_xor(p1, off, 64);
    p2 += __shfl_xor(p2, off, 64);
    p3 += __shfl_xor(p3, off, 64);
  }
  if (tid < BCH) {
    float v = (tid == 0) ? p0 : (tid == 1) ? p1 : (tid == 2) ? p2 : p3;
    outp[(size_t)(b0 + tid) * T_LEN + t] = v + bo;
  }
}

__global__ void __launch_bounds__(512) lstm_fused(
    const float* __restrict__ xin, const float* __restrict__ Wih1,
    const float* __restrict__ bih1, const float* __restrict__ bhh1,
    const float* __restrict__ Whh1, const float* __restrict__ Wih2,
    const float* __restrict__ Whh2, int sk, int sj,
    const float* __restrict__ bih2, const float* __restrict__ bhh2,
    const float* __restrict__ Wout, const float* __restrict__ bout,
    float* __restrict__ outp) {
  __shared__ float4 h1buf[HID];
  __shared__ float4 h2buf[HID];
  __shared__ float4 g1[G4];
  __shared__ float4 g2[G4];
  __shared__ float xb[2][BCH];

  const int tid = threadIdx.x;
  const int b0 = blockIdx.x * BCH;
  const int gt = tid >> 7;

  float bias1 = bih1[tid] + bhh1[tid];
  float bias2 = bih2[tid] + bhh2[tid];
  float wi1 = Wih1[tid];
  float c1_0 = 0.f, c1_1 = 0.f, c1_2 = 0.f, c1_3 = 0.f;
  float c2_0 = 0.f, c2_1 = 0.f, c2_2 = 0.f, c2_3 = 0.f;
  float wo0 = 0.f, wo1 = 0.f, bo = 0.f;
  if (tid < 64) { wo0 = Wout[tid]; wo1 = Wout[tid + 64]; bo = bout[0]; }
  if (tid < HID) {
    h1buf[tid] = make_float4(0.f, 0.f, 0.f, 0.f);
    h2buf[tid] = make_float4(0.f, 0.f, 0.f, 0.f);
  }
  if (tid < BCH) xb[0][tid] = xin[(b0 + tid) * T_LEN];
  __syncthreads();

  const float* wp1  = Whh1 + tid * sj;
  const float* wp2  = Whh2 + tid * sj;
  const float* wpi2 = Wih2 + tid * sj;

  for (int t = 0; t < T_LEN; ++t) {
    float xpref = 0.f;
    if ((tid & ~3) == 128 && (t + 1) < T_LEN)
      xpref = xin[(b0 + (tid & 3)) * T_LEN + t + 1];

    if (tid < 64 && t > 0) store_out4(h2buf, wo0, wo1, bo, tid, b0, outp, t - 1);

    float xv0 = xb[t & 1][0], xv1 = xb[t & 1][1];
    float xv2 = xb[t & 1][2], xv3 = xb[t & 1][3];
    float a10 = fmaf(wi1, xv0, bias1);
    float a11 = fmaf(wi1, xv1, bias1);
    float a12 = fmaf(wi1, xv2, bias1);
    float a13 = fmaf(wi1, xv3, bias1);
    float a20 = bias2, a21 = bias2, a22 = bias2, a23 = bias2;
#pragma unroll 8
    for (int k = 0; k < HID; ++k) {
      float w1 = wp1[k * sk];
      float w2 = wp2[k * sk];
      float4 hv1 = h1buf[k];
      float4 hv2 = h2buf[k];
      a10 = fmaf(w1, hv1.x, a10);
      a11 = fmaf(w1, hv1.y, a11);
      a12 = fmaf(w1, hv1.z, a12);
      a13 = fmaf(w1, hv1.w, a13);
      a20 = fmaf(w2, hv2.x, a20);
      a21 = fmaf(w2, hv2.y, a21);
      a22 = fmaf(w2, hv2.z, a22);
      a23 = fmaf(w2, hv2.w, a23);
    }
    float4 A1v;
    A1v.x = gact(a10, gt); A1v.y = gact(a11, gt);
    A1v.z = gact(a12, gt); A1v.w = gact(a13, gt);
    g1[tid] = A1v;
    __syncthreads();

    if (tid < HID) {
      float4 iv = g1[tid], fv = g1[tid + HID];
      float4 gv = g1[tid + 2 * HID], ov = g1[tid + 3 * HID];
      c1_0 = fmaf(fv.x, c1_0, iv.x * gv.x);
      c1_1 = fmaf(fv.y, c1_1, iv.y * gv.y);
      c1_2 = fmaf(fv.z, c1_2, iv.z * gv.z);
      c1_3 = fmaf(fv.w, c1_3, iv.w * gv.w);
      float4 h;
      h.x = ov.x * ftanh(c1_0);
      h.y = ov.y * ftanh(c1_1);
      h.z = ov.z * ftanh(c1_2);
      h.w = ov.w * ftanh(c1_3);
      h1buf[tid] = h;
    }
    __syncthreads();

#pragma unroll 8
    for (int k = 0; k < HID; ++k) {
      float wv = wpi2[k * sk];
      float4 hv = h1buf[k];
      a20 = fmaf(wv, hv.x, a20);
      a21 = fmaf(wv, hv.y, a21);
      a22 = fmaf(wv, hv.z, a22);
      a23 = fmaf(wv, hv.w, a23);
    }
    float4 A2v;
    A2v.x = gact(a20, gt); A2v.y = gact(a21, gt);
    A2v.z = gact(a22, gt); A2v.w = gact(a23, gt);
    g2[tid] = A2v;
    __syncthreads();

    if (tid < HID) {
      float4 iv = g2[tid], fv = g2[tid + HID];
      float4 gv = g2[tid + 2 * HID], ov = g2[tid + 3 * HID];
      c2_0 = fmaf(fv.x, c2_0, iv.x * gv.x);
      c2_1 = fmaf(fv.y, c2_1, iv.y * gv.y);
      c2_2 = fmaf(fv.z, c2_2, iv.z * gv.z);
      c2_3 = fmaf(fv.w, c2_3, iv.w * gv.w);
      float4 h;
      h.x = ov.x * ftanh(c2_0);
      h.y = ov.y * ftanh(c2_1);
      h.z = ov.z * ftanh(c2_2);
      h.w = ov.w * ftanh(c2_3);
      h2buf[tid] = h;
    } else if ((tid & ~3) == 128 && (t + 1) < T_LEN) {
      xb[(t + 1) & 1][tid & 3] = xpref;
    }
    __syncthreads();
  }
  if (tid < 64) store_out4(h2buf, wo0, wo1, bo, tid, b0, outp, T_LEN - 1);
}

extern "C" void kernel_launch(void* const* d_in, const int* in_sizes, int n_in,
                              void* d_out, int out_size, void* d_ws, size_t ws_size,
                              hipStream_t stream) {
  const float* xin  = (const float*)d_in[0];
  const float* Wih1 = (const float*)d_in[1];
  const float* Whh1 = (const float*)d_in[2];
  const float* bih1 = (const float*)d_in[3];
  const float* bhh1 = (const float*)d_in[4];
  const float* Wih2 = (const float*)d_in[5];
  const float* Whh2 = (const float*)d_in[6];
  const float* bih2 = (const float*)d_in[7];
  const float* bhh2 = (const float*)d_in[8];
  const float* Wout = (const float*)d_in[9];
  const float* bout = (const float*)d_in[10];
  float* outp = (float*)d_out;

  const size_t needFr = (size_t)384 * 64 * sizeof(uint4);  // 384 KB
  if (ws_size >= needFr) {
    uint4* wfrag = (uint4*)d_ws;
    pack_frag3<<<96, 256, 0, stream>>>(Whh1, Whh2, Wih2, wfrag);
    lstm_wide<<<NG2, 1024, 0, stream>>>(
        xin, Wih1, bih1, bhh1, wfrag, bih2, bhh2, Wout, bout, outp);
    return;
  }

  // fallback: round-1 fp32 kernel
  size_t need = (size_t)3 * G4 * HID * sizeof(float);
  if (ws_size >= need) {
    float* wt = (float*)d_ws;
    transpose_w<<<dim3(128, 3), 512, 0, stream>>>(Whh1, Wih2, Whh2, wt);
    lstm_fused<<<NG, 512, 0, stream>>>(
        xin, Wih1, bih1, bhh1,
        wt, wt + (size_t)G4 * HID, wt + (size_t)2 * G4 * HID, G4, 1,
        bih2, bhh2, Wout, bout, outp);
  } else {
    lstm_fused<<<NG, 512, 0, stream>>>(
        xin, Wih1, bih1, bhh1,
        Whh1, Wih2, Whh2, 1, HID,
        bih2, bhh2, Wout, bout, outp);
  }
}

// Round 9
// 2571.114 us; speedup vs baseline: 2.2017x; 2.2017x over previous
//
#include <hip/hip_runtime.h>

#define T_LEN 1024
#define HID   128
#define G4    512
#define NG    128      // fallback WGs
#define BCH   4        // fallback batch/WG
#define HB_STR 136     // halves per batch-col row

typedef _Float16 h2_t   __attribute__((ext_vector_type(2)));
typedef _Float16 f16x8  __attribute__((ext_vector_type(8)));
typedef float    f32x4n __attribute__((ext_vector_type(4)));

__device__ __forceinline__ float fsig(float v) {
  return __builtin_amdgcn_rcpf(1.0f + __expf(-v));
}
__device__ __forceinline__ float ftanh(float v) {
  float a = fabsf(v);
  float e = __expf(-2.0f * a);
  float t = (1.0f - e) * __builtin_amdgcn_rcpf(1.0f + e);
  return copysignf(t, v);
}

#define MFMA16(A, B, C) __builtin_amdgcn_mfma_f32_16x16x32_f16( \
    __builtin_bit_cast(f16x8, (A)), (B), (C), 0, 0, 0)

// ---------------------------------------------------------------------------
// Pack fp32 weights into MFMA A-fragments (fp16), gate-tiled per wave
// (identical to R5/R6/R7 — validated): dst[((m*8+w)*16 + g*4+kt)*64 + l] =
// 8 halves of row = g*128 + 16w + (l&15), k = 32*kt + (l>>4)*8.
// m: 0=Whh1, 1=Whh2, 2=Wih2.
// ---------------------------------------------------------------------------
__global__ void __launch_bounds__(256) pack_frag2(
    const float* __restrict__ wa, const float* __restrict__ wb,
    const float* __restrict__ wc, uint4* __restrict__ dst) {
  int idx = blockIdx.x * 256 + threadIdx.x;   // 0..24575
  int l = idx & 63;
  int f = (idx >> 6) & 15;
  int w = (idx >> 10) & 7;
  int m = idx >> 13;
  const float* src = (m == 0) ? wa : (m == 1) ? wb : wc;
  int row = (f >> 2) * HID + 16 * w + (l & 15);
  int k0  = 32 * (f & 3) + (l >> 4) * 8;
  const float* s = src + (size_t)row * HID + k0;
  unsigned int r[4];
#pragma unroll
  for (int q = 0; q < 4; ++q) {
    h2_t h;
    h.x = (_Float16)s[2 * q];
    h.y = (_Float16)s[2 * q + 1];
    r[q] = __builtin_bit_cast(unsigned int, h);
  }
  dst[idx] = make_uint4(r[0], r[1], r[2], r[3]);
}

// ---------------------------------------------------------------------------
// R9: 256 WGs x 512 thr (8 waves, 2/SIMD), 2 batches/WG, ONE WG per CU
// (LDS padded >80KB). R7 3-phase schedule; weights as register/AGPR-resident
// A-fragments; NO global memory ops inside the t-loop (x preloaded to LDS,
// out accumulated in LDS, stored once at the end).
// Act role: thread -> (u = tid>>2, g = tid&3), both batches in-thread;
// 4-lane gate cluster combined via shfl_xor(1,2,3) (R8-validated).
// g-buffers stride-9 [u][g][b] -> scatter/gather bank-conflict-free.
// ---------------------------------------------------------------------------
__global__ void __launch_bounds__(512, 2) lstm_v9(
    const float* __restrict__ xin, const float* __restrict__ Wih1,
    const float* __restrict__ bih1, const float* __restrict__ bhh1,
    const uint4* __restrict__ wfrag,
    const float* __restrict__ bih2, const float* __restrict__ bhh2,
    const float* __restrict__ Wout, const float* __restrict__ bout,
    float* __restrict__ outp)
{
  __shared__ _Float16 hB1[16 * HB_STR];
  __shared__ _Float16 hB2[16 * HB_STR];
  __shared__ float    g1b[HID * 9];     // [u]*9 + g*2 + b  (word 8 = pad)
  __shared__ float    g2b[HID * 9];
  __shared__ float    prt[8][2];
  __shared__ float    xbuf[2][T_LEN];   // preloaded input
  __shared__ float    outb[2][T_LEN];   // output accumulator
  __shared__ float    pad[12544];       // pushes LDS > 80KB -> 1 WG/CU

  const int tid = threadIdx.x;
  const int l   = tid & 63;
  const int w   = tid >> 6;        // wave 0..7
  const int col = l & 15;
  const int q   = l >> 4;
  const int b0  = blockIdx.x * 2;
  const int g   = tid & 3;         // gate 0:i 1:f 2:g 3:o
  const int u   = tid >> 2;        // unit 0..127

  // ---- A-fragments into registers/AGPRs (one-time) ----
  f32x4n A1[16], A2[16], AI[16];
#pragma unroll
  for (int f = 0; f < 16; ++f) {
    A1[f] = __builtin_bit_cast(f32x4n, wfrag[((0 * 8 + w) * 16 + f) * 64 + l]);
    A2[f] = __builtin_bit_cast(f32x4n, wfrag[((1 * 8 + w) * 16 + f) * 64 + l]);
    AI[f] = __builtin_bit_cast(f32x4n, wfrag[((2 * 8 + w) * 16 + f) * 64 + l]);
  }
#pragma unroll
  for (int f = 0; f < 16; ++f)
    asm volatile("" : "+v"(A1[f]), "+v"(A2[f]), "+v"(AI[f]));

  // ---- per-lane constants for act role (u,g) ----
  const float b1c = bih1[g * HID + u] + bhh1[g * HID + u];
  const float w1c = Wih1[g * HID + u];
  const float b2c = bih2[g * HID + u] + bhh2[g * HID + u];
  const float wou = Wout[u];
  float c1b0 = 0.f, c1b1 = 0.f, c2b0 = 0.f, c2b1 = 0.f;

  // ---- init LDS: zero h buffers, preload x, park bo in pad[0] ----
  {
    unsigned int* z1 = (unsigned int*)hB1;
    unsigned int* z2 = (unsigned int*)hB2;
    for (int i = tid; i < 16 * HB_STR / 2; i += 512) { z1[i] = 0u; z2[i] = 0u; }
#pragma unroll
    for (int i = 0; i < 4; ++i) {
      int idx = tid + 512 * i;
      int bq  = idx >> 10;
      int ps  = idx & 1023;
      xbuf[bq][ps] = xin[(size_t)(b0 + bq) * T_LEN + ps];
    }
    if (tid == 0) pad[0] = bout[0];
  }
  __syncthreads();

  // ---- prologue: h1(0) = layer1(x(0), h=0, c=0) ----
  {
    float x0 = xbuf[0][0], x1 = xbuf[1][0];
    float v0 = fmaf(w1c, x0, b1c);
    float v1 = fmaf(w1c, x1, b1c);
    float a0 = (g == 2) ? ftanh(v0) : fsig(v0);
    float a1 = (g == 2) ? ftanh(v1) : fsig(v1);
    float tg0 = __shfl_xor(a0, 2, 64), so0 = __shfl_xor(a0, 3, 64);
    float tg1 = __shfl_xor(a1, 2, 64), so1 = __shfl_xor(a1, 3, 64);
    float cn0 = a0 * tg0;            // i*g (f*c0 = 0)
    float cn1 = a1 * tg1;
    if (g == 0) {
      c1b0 = cn0; c1b1 = cn1;
      hB1[0 * HB_STR + u] = (_Float16)(so0 * ftanh(cn0));
      hB1[1 * HB_STR + u] = (_Float16)(so1 * ftanh(cn1));
    }
  }
  __syncthreads();

  const int boff  = col * HB_STR + q * 8;
  const int urow0 = 16 * w + 4 * q;

  f32x4n C2i = {0,0,0,0}, C2f = {0,0,0,0}, C2g = {0,0,0,0}, C2o = {0,0,0,0};

  for (int t = 0; t < T_LEN; ++t) {
    // ================= A: MFMA burst on h1(t) =================
    f16x8 Bh0 = *reinterpret_cast<const f16x8*>(&hB1[boff +  0]);
    f16x8 Bh1 = *reinterpret_cast<const f16x8*>(&hB1[boff + 32]);
    f16x8 Bh2 = *reinterpret_cast<const f16x8*>(&hB1[boff + 64]);
    f16x8 Bh3 = *reinterpret_cast<const f16x8*>(&hB1[boff + 96]);

    f32x4n C1i = {0,0,0,0}, C1f = {0,0,0,0}, C1g = {0,0,0,0}, C1o = {0,0,0,0};

    C1i = MFMA16(A1[ 0], Bh0, C1i); C1i = MFMA16(A1[ 1], Bh1, C1i);
    C1i = MFMA16(A1[ 2], Bh2, C1i); C1i = MFMA16(A1[ 3], Bh3, C1i);
    C1f = MFMA16(A1[ 4], Bh0, C1f); C1f = MFMA16(A1[ 5], Bh1, C1f);
    C1f = MFMA16(A1[ 6], Bh2, C1f); C1f = MFMA16(A1[ 7], Bh3, C1f);
    C1g = MFMA16(A1[ 8], Bh0, C1g); C1g = MFMA16(A1[ 9], Bh1, C1g);
    C1g = MFMA16(A1[10], Bh2, C1g); C1g = MFMA16(A1[11], Bh3, C1g);
    C1o = MFMA16(A1[12], Bh0, C1o); C1o = MFMA16(A1[13], Bh1, C1o);
    C1o = MFMA16(A1[14], Bh2, C1o); C1o = MFMA16(A1[15], Bh3, C1o);

    C2i = MFMA16(AI[ 0], Bh0, C2i); C2i = MFMA16(AI[ 1], Bh1, C2i);
    C2i = MFMA16(AI[ 2], Bh2, C2i); C2i = MFMA16(AI[ 3], Bh3, C2i);
    C2f = MFMA16(AI[ 4], Bh0, C2f); C2f = MFMA16(AI[ 5], Bh1, C2f);
    C2f = MFMA16(AI[ 6], Bh2, C2f); C2f = MFMA16(AI[ 7], Bh3, C2f);
    C2g = MFMA16(AI[ 8], Bh0, C2g); C2g = MFMA16(AI[ 9], Bh1, C2g);
    C2g = MFMA16(AI[10], Bh2, C2g); C2g = MFMA16(AI[11], Bh3, C2g);
    C2o = MFMA16(AI[12], Bh0, C2o); C2o = MFMA16(AI[13], Bh1, C2o);
    C2o = MFMA16(AI[14], Bh2, C2o); C2o = MFMA16(AI[15], Bh3, C2o);

    if (col < 2) {
#pragma unroll
      for (int r = 0; r < 4; ++r) {
        int u_ = urow0 + r;
        g2b[u_ * 9 + 0 + col] = C2i[r];
        g2b[u_ * 9 + 2 + col] = C2f[r];
        g2b[u_ * 9 + 4 + col] = C2g[r];
        g2b[u_ * 9 + 6 + col] = C2o[r];
      }
    }
    __syncthreads();   // ---- barrier 1 ----

    // ================= B: state-2 + out partial; scatter C1 =================
    {
      float v0 = g2b[u * 9 + 2 * g + 0] + b2c;
      float v1 = g2b[u * 9 + 2 * g + 1] + b2c;
      float a0 = (g == 2) ? ftanh(v0) : fsig(v0);
      float a1 = (g == 2) ? ftanh(v1) : fsig(v1);
      float sf0 = __shfl_xor(a0, 1, 64), tg0 = __shfl_xor(a0, 2, 64), so0 = __shfl_xor(a0, 3, 64);
      float sf1 = __shfl_xor(a1, 1, 64), tg1 = __shfl_xor(a1, 2, 64), so1 = __shfl_xor(a1, 3, 64);
      float cn0 = fmaf(sf0, c2b0, a0 * tg0);   // valid at g==0
      float cn1 = fmaf(sf1, c2b1, a1 * tg1);
      float h20 = so0 * ftanh(cn0);
      float h21 = so1 * ftanh(cn1);
      float po0 = 0.f, po1 = 0.f;
      if (g == 0) {
        c2b0 = cn0; c2b1 = cn1;
        hB2[0 * HB_STR + u] = (_Float16)h20;
        hB2[1 * HB_STR + u] = (_Float16)h21;
        po0 = wou * h20;
        po1 = wou * h21;
      }
      po0 += __shfl_xor(po0, 4, 64);  po1 += __shfl_xor(po1, 4, 64);
      po0 += __shfl_xor(po0, 8, 64);  po1 += __shfl_xor(po1, 8, 64);
      po0 += __shfl_xor(po0, 16, 64); po1 += __shfl_xor(po1, 16, 64);
      po0 += __shfl_xor(po0, 32, 64); po1 += __shfl_xor(po1, 32, 64);
      if (l == 0) { prt[w][0] = po0; prt[w][1] = po1; }
    }
    if (col < 2) {
#pragma unroll
      for (int r = 0; r < 4; ++r) {
        int u_ = urow0 + r;
        g1b[u_ * 9 + 0 + col] = C1i[r];
        g1b[u_ * 9 + 2 + col] = C1f[r];
        g1b[u_ * 9 + 4 + col] = C1g[r];
        g1b[u_ * 9 + 6 + col] = C1o[r];
      }
    }
    __syncthreads();   // ---- barrier 2 ----

    // ================= CD: out accumulate + carry MFMA + state-1 =================
    if (tid < 2) {
      float s = prt[0][tid] + prt[1][tid] + prt[2][tid] + prt[3][tid]
              + prt[4][tid] + prt[5][tid] + prt[6][tid] + prt[7][tid];
      outb[tid][t] = s;
    }

    f16x8 Dh0 = *reinterpret_cast<const f16x8*>(&hB2[boff +  0]);
    f16x8 Dh1 = *reinterpret_cast<const f16x8*>(&hB2[boff + 32]);
    f16x8 Dh2 = *reinterpret_cast<const f16x8*>(&hB2[boff + 64]);
    f16x8 Dh3 = *reinterpret_cast<const f16x8*>(&hB2[boff + 96]);

    C2i = (f32x4n){0,0,0,0};
    C2f = (f32x4n){0,0,0,0};
    C2g = (f32x4n){0,0,0,0};
    C2o = (f32x4n){0,0,0,0};
    C2i = MFMA16(A2[ 0], Dh0, C2i); C2i = MFMA16(A2[ 1], Dh1, C2i);
    C2i = MFMA16(A2[ 2], Dh2, C2i); C2i = MFMA16(A2[ 3], Dh3, C2i);
    C2f = MFMA16(A2[ 4], Dh0, C2f); C2f = MFMA16(A2[ 5], Dh1, C2f);
    C2f = MFMA16(A2[ 6], Dh2, C2f); C2f = MFMA16(A2[ 7], Dh3, C2f);
    C2g = MFMA16(A2[ 8], Dh0, C2g); C2g = MFMA16(A2[ 9], Dh1, C2g);
    C2g = MFMA16(A2[10], Dh2, C2g); C2g = MFMA16(A2[11], Dh3, C2g);
    C2o = MFMA16(A2[12], Dh0, C2o); C2o = MFMA16(A2[13], Dh1, C2o);
    C2o = MFMA16(A2[14], Dh2, C2o); C2o = MFMA16(A2[15], Dh3, C2o);

    {
      int tn = (t + 1) & (T_LEN - 1);     // t=1023 computes unused h1(1024)
      float x0 = xbuf[0][tn], x1 = xbuf[1][tn];
      float v0 = g1b[u * 9 + 2 * g + 0] + fmaf(w1c, x0, b1c);
      float v1 = g1b[u * 9 + 2 * g + 1] + fmaf(w1c, x1, b1c);
      float a0 = (g == 2) ? ftanh(v0) : fsig(v0);
      float a1 = (g == 2) ? ftanh(v1) : fsig(v1);
      float sf0 = __shfl_xor(a0, 1, 64), tg0 = __shfl_xor(a0, 2, 64), so0 = __shfl_xor(a0, 3, 64);
      float sf1 = __shfl_xor(a1, 1, 64), tg1 = __shfl_xor(a1, 2, 64), so1 = __shfl_xor(a1, 3, 64);
      float cn0 = fmaf(sf0, c1b0, a0 * tg0);
      float cn1 = fmaf(sf1, c1b1, a1 * tg1);
      if (g == 0) {
        c1b0 = cn0; c1b1 = cn1;
        hB1[0 * HB_STR + u] = (_Float16)(so0 * ftanh(cn0));
        hB1[1 * HB_STR + u] = (_Float16)(so1 * ftanh(cn1));
      }
    }
    __syncthreads();   // ---- barrier 3 ----
  }

  // ---- epilogue: one coalesced store of the whole output ----
  float pbo = pad[0];
#pragma unroll
  for (int i = 0; i < 4; ++i) {
    int idx = tid + 512 * i;
    int bq  = idx >> 10;
    int ps  = idx & 1023;
    outp[(size_t)(b0 + bq) * T_LEN + ps] = outb[bq][ps] + pbo;
  }
}

// ---------------------------------------------------------------------------
// Fallback (round-1, known-correct fp32 path)
// ---------------------------------------------------------------------------
__global__ void __launch_bounds__(512) transpose_w(
    const float* __restrict__ w1, const float* __restrict__ w2,
    const float* __restrict__ w3, float* __restrict__ o) {
  int m = blockIdx.y;
  const float* src = (m == 0) ? w1 : (m == 1) ? w2 : w3;
  float* dst = o + (size_t)m * G4 * HID;
  int idx = blockIdx.x * 512 + threadIdx.x;
  int j = idx >> 7;
  int k = idx & (HID - 1);
  dst[k * G4 + j] = src[idx];
}

__device__ __forceinline__ float gact(float v, int gt) {
  return (gt == 2) ? ftanh(v) : fsig(v);
}

__device__ __forceinline__ void store_out4(const float4* h2buf, float wo0, float wo1,
                                           float bo, int tid, int b0,
                                           float* __restrict__ outp, int t) {
  float4 ha = h2buf[tid];
  float4 hb = h2buf[tid + 64];
  float p0 = wo0 * ha.x + wo1 * hb.x;
  float p1 = wo0 * ha.y + wo1 * hb.y;
  float p2 = wo0 * ha.z + wo1 * hb.z;
  float p3 = wo0 * ha.w + wo1 * hb.w;
#pragma unroll
  for (int off = 1; off < 64; off <<= 1) {
    p0 += __shfl_xor(p0, off, 64);
    p1 += __shfl_xor(p1, off, 64);
    p2 += __shfl_xor(p2, off, 64);
    p3 += __shfl_xor(p3, off, 64);
  }
  if (tid < BCH) {
    float v = (tid == 0) ? p0 : (tid == 1) ? p1 : (tid == 2) ? p2 : p3;
    outp[(size_t)(b0 + tid) * T_LEN + t] = v + bo;
  }
}

__global__ void __launch_bounds__(512) lstm_fused(
    const float* __restrict__ xin, const float* __restrict__ Wih1,
    const float* __restrict__ bih1, const float* __restrict__ bhh1,
    const float* __restrict__ Whh1, const float* __restrict__ Wih2,
    const float* __restrict__ Whh2, int sk, int sj,
    const float* __restrict__ bih2, const float* __restrict__ bhh2,
    const float* __restrict__ Wout, const float* __restrict__ bout,
    float* __restrict__ outp) {
  __shared__ float4 h1buf[HID];
  __shared__ float4 h2buf[HID];
  __shared__ float4 g1[G4];
  __shared__ float4 g2[G4];
  __shared__ float xb[2][BCH];

  const int tid = threadIdx.x;
  const int b0 = blockIdx.x * BCH;
  const int gt = tid >> 7;

  float bias1 = bih1[tid] + bhh1[tid];
  float bias2 = bih2[tid] + bhh2[tid];
  float wi1 = Wih1[tid];
  float c1_0 = 0.f, c1_1 = 0.f, c1_2 = 0.f, c1_3 = 0.f;
  float c2_0 = 0.f, c2_1 = 0.f, c2_2 = 0.f, c2_3 = 0.f;
  float wo0 = 0.f, wo1 = 0.f, bo = 0.f;
  if (tid < 64) { wo0 = Wout[tid]; wo1 = Wout[tid + 64]; bo = bout[0]; }
  if (tid < HID) {
    h1buf[tid] = make_float4(0.f, 0.f, 0.f, 0.f);
    h2buf[tid] = make_float4(0.f, 0.f, 0.f, 0.f);
  }
  if (tid < BCH) xb[0][tid] = xin[(b0 + tid) * T_LEN];
  __syncthreads();

  const float* wp1  = Whh1 + tid * sj;
  const float* wp2  = Whh2 + tid * sj;
  const float* wpi2 = Wih2 + tid * sj;

  for (int t = 0; t < T_LEN; ++t) {
    float xpref = 0.f;
    if ((tid & ~3) == 128 && (t + 1) < T_LEN)
      xpref = xin[(b0 + (tid & 3)) * T_LEN + t + 1];

    if (tid < 64 && t > 0) store_out4(h2buf, wo0, wo1, bo, tid, b0, outp, t - 1);

    float xv0 = xb[t & 1][0], xv1 = xb[t & 1][1];
    float xv2 = xb[t & 1][2], xv3 = xb[t & 1][3];
    float a10 = fmaf(wi1, xv0, bias1);
    float a11 = fmaf(wi1, xv1, bias1);
    float a12 = fmaf(wi1, xv2, bias1);
    float a13 = fmaf(wi1, xv3, bias1);
    float a20 = bias2, a21 = bias2, a22 = bias2, a23 = bias2;
#pragma unroll 8
    for (int k = 0; k < HID; ++k) {
      float w1 = wp1[k * sk];
      float w2 = wp2[k * sk];
      float4 hv1 = h1buf[k];
      float4 hv2 = h2buf[k];
      a10 = fmaf(w1, hv1.x, a10);
      a11 = fmaf(w1, hv1.y, a11);
      a12 = fmaf(w1, hv1.z, a12);
      a13 = fmaf(w1, hv1.w, a13);
      a20 = fmaf(w2, hv2.x, a20);
      a21 = fmaf(w2, hv2.y, a21);
      a22 = fmaf(w2, hv2.z, a22);
      a23 = fmaf(w2, hv2.w, a23);
    }
    float4 A1v;
    A1v.x = gact(a10, gt); A1v.y = gact(a11, gt);
    A1v.z = gact(a12, gt); A1v.w = gact(a13, gt);
    g1[tid] = A1v;
    __syncthreads();

    if (tid < HID) {
      float4 iv = g1[tid], fv = g1[tid + HID];
      float4 gv = g1[tid + 2 * HID], ov = g1[tid + 3 * HID];
      c1_0 = fmaf(fv.x, c1_0, iv.x * gv.x);
      c1_1 = fmaf(fv.y, c1_1, iv.y * gv.y);
      c1_2 = fmaf(fv.z, c1_2, iv.z * gv.z);
      c1_3 = fmaf(fv.w, c1_3, iv.w * gv.w);
      float4 h;
      h.x = ov.x * ftanh(c1_0);
      h.y = ov.y * ftanh(c1_1);
      h.z = ov.z * ftanh(c1_2);
      h.w = ov.w * ftanh(c1_3);
      h1buf[tid] = h;
    }
    __syncthreads();

#pragma unroll 8
    for (int k = 0; k < HID; ++k) {
      float wv = wpi2[k * sk];
      float4 hv = h1buf[k];
      a20 = fmaf(wv, hv.x, a20);
      a21 = fmaf(wv, hv.y, a21);
      a22 = fmaf(wv, hv.z, a22);
      a23 = fmaf(wv, hv.w, a23);
    }
    float4 A2v;
    A2v.x = gact(a20, gt); A2v.y = gact(a21, gt);
    A2v.z = gact(a22, gt); A2v.w = gact(a23, gt);
    g2[tid] = A2v;
    __syncthreads();

    if (tid < HID) {
      float4 iv = g2[tid], fv = g2[tid + HID];
      float4 gv = g2[tid + 2 * HID], ov = g2[tid + 3 * HID];
      c2_0 = fmaf(fv.x, c2_0, iv.x * gv.x);
      c2_1 = fmaf(fv.y, c2_1, iv.y * gv.y);
      c2_2 = fmaf(fv.z, c2_2, iv.z * gv.z);
      c2_3 = fmaf(fv.w, c2_3, iv.w * gv.w);
      float4 h;
      h.x = ov.x * ftanh(c2_0);
      h.y = ov.y * ftanh(c2_1);
      h.z = ov.z * ftanh(c2_2);
      h.w = ov.w * ftanh(c2_3);
      h2buf[tid] = h;
    } else if ((tid & ~3) == 128 && (t + 1) < T_LEN) {
      xb[(t + 1) & 1][tid & 3] = xpref;
    }
    __syncthreads();
  }
  if (tid < 64) store_out4(h2buf, wo0, wo1, bo, tid, b0, outp, T_LEN - 1);
}

extern "C" void kernel_launch(void* const* d_in, const int* in_sizes, int n_in,
                              void* d_out, int out_size, void* d_ws, size_t ws_size,
                              hipStream_t stream) {
  const float* xin  = (const float*)d_in[0];
  const float* Wih1 = (const float*)d_in[1];
  const float* Whh1 = (const float*)d_in[2];
  const float* bih1 = (const float*)d_in[3];
  const float* bhh1 = (const float*)d_in[4];
  const float* Wih2 = (const float*)d_in[5];
  const float* Whh2 = (const float*)d_in[6];
  const float* bih2 = (const float*)d_in[7];
  const float* bhh2 = (const float*)d_in[8];
  const float* Wout = (const float*)d_in[9];
  const float* bout = (const float*)d_in[10];
  float* outp = (float*)d_out;

  const size_t needFr = (size_t)3 * 8 * 16 * 64 * sizeof(uint4);  // 384 KB
  if (ws_size >= needFr) {
    uint4* wfrag = (uint4*)d_ws;
    pack_frag2<<<96, 256, 0, stream>>>(Whh1, Whh2, Wih2, wfrag);
    lstm_v9<<<256, 512, 0, stream>>>(
        xin, Wih1, bih1, bhh1, wfrag, bih2, bhh2, Wout, bout, outp);
    return;
  }

  // fallback: round-1 fp32 kernel
  size_t need = (size_t)3 * G4 * HID * sizeof(float);
  if (ws_size >= need) {
    float* wt = (float*)d_ws;
    transpose_w<<<dim3(128, 3), 512, 0, stream>>>(Whh1, Wih2, Whh2, wt);
    lstm_fused<<<NG, 512, 0, stream>>>(
        xin, Wih1, bih1, bhh1,
        wt, wt + (size_t)G4 * HID, wt + (size_t)2 * G4 * HID, G4, 1,
        bih2, bhh2, Wout, bout, outp);
  } else {
    lstm_fused<<<NG, 512, 0, stream>>>(
        xin, Wih1, bih1, bhh1,
        Whh1, Wih2, Whh2, 1, HID,
        bih2, bhh2, Wout, bout, outp);
  }
}

// Round 10
// 2182.490 us; speedup vs baseline: 2.5938x; 1.1781x over previous
//
#include <hip/hip_runtime.h>

#define T_LEN 1024
#define HID   128
#define G4    512
#define NG    128      // fallback WGs
#define BCH   4        // fallback batch/WG
#define HB_STR 136     // halves per batch row of h buffers

typedef _Float16 h2_t   __attribute__((ext_vector_type(2)));
typedef _Float16 f16x8  __attribute__((ext_vector_type(8)));
typedef float    f32x4n __attribute__((ext_vector_type(4)));

__device__ __forceinline__ float fsig(float v) {
  return __builtin_amdgcn_rcpf(1.0f + __expf(-v));
}
__device__ __forceinline__ float ftanh(float v) {
  float a = fabsf(v);
  float e = __expf(-2.0f * a);
  float t = (1.0f - e) * __builtin_amdgcn_rcpf(1.0f + e);
  return copysignf(t, v);
}
__device__ __forceinline__ float fdot2(unsigned int a, unsigned int b, float c) {
  union { unsigned int u; h2_t h; } ca, cb;
  ca.u = a; cb.u = b;
  return __builtin_amdgcn_fdot2(ca.h, cb.h, c, false);
}

#define MFMA16(A, B, C) __builtin_amdgcn_mfma_f32_16x16x32_f16( \
    __builtin_bit_cast(f16x8, (A)), (B), (C), 0, 0, 0)

// ---------------------------------------------------------------------------
// Pack fp32 weights into MFMA A-fragments (fp16), gate-tiled per wave
// (identical to R5..R9 — validated): dst[((m*8+w)*16 + g*4+kt)*64 + l] =
// 8 halves of row = g*128 + 16w + (l&15), k = 32*kt + (l>>4)*8.
// m: 0=Whh1, 1=Whh2, 2=Wih2.
// ---------------------------------------------------------------------------
__global__ void __launch_bounds__(256) pack_frag2(
    const float* __restrict__ wa, const float* __restrict__ wb,
    const float* __restrict__ wc, uint4* __restrict__ dst) {
  int idx = blockIdx.x * 256 + threadIdx.x;   // 0..24575
  int l = idx & 63;
  int f = (idx >> 6) & 15;
  int w = (idx >> 10) & 7;
  int m = idx >> 13;
  const float* src = (m == 0) ? wa : (m == 1) ? wb : wc;
  int row = (f >> 2) * HID + 16 * w + (l & 15);
  int k0  = 32 * (f & 3) + (l >> 4) * 8;
  const float* s = src + (size_t)row * HID + k0;
  unsigned int r[4];
#pragma unroll
  for (int qq = 0; qq < 4; ++qq) {
    h2_t h;
    h.x = (_Float16)s[2 * qq];
    h.y = (_Float16)s[2 * qq + 1];
    r[qq] = __builtin_bit_cast(unsigned int, h);
  }
  dst[idx] = make_uint4(r[0], r[1], r[2], r[3]);
}

// ---------------------------------------------------------------------------
// R10: 256 WGs x 512 thr, 2 batches/WG, 2 barriers/step.
//  M: 48 MFMA (C1 = Whh1*h1(t) -> gates1(t+1); C2 = Whh2*h2(t-1)+Wih2*h1(t)
//     = gates2(t)); broadcast B-reads (col&1); b128 scatter to g-buffers;
//     wave0 computes out(t-1) = wo.h2(t-1) via fdot2 on the Dh fragments.
//  V: role (u = tid>>2, b = (tid>>1)&1, L = tid&1): L=0 does layer-2 state
//     (h2(t)), L=1 does layer-1 state (h1(t+1)); 4 conflict-free gathers,
//     private c, no shuffles.
// x preloaded to LDS; out staged in LDS; no global ops in the loop.
// ---------------------------------------------------------------------------
__global__ void __launch_bounds__(512, 2) lstm_v10(
    const float* __restrict__ xin, const float* __restrict__ Wih1,
    const float* __restrict__ bih1, const float* __restrict__ bhh1,
    const uint4* __restrict__ wfrag,
    const float* __restrict__ bih2, const float* __restrict__ bhh2,
    const float* __restrict__ Wout, const float* __restrict__ bout,
    float* __restrict__ outp)
{
  __shared__ __align__(16) _Float16 hB1[2 * HB_STR];
  __shared__ __align__(16) _Float16 hB2[2 * HB_STR];
  __shared__ __align__(16) _Float16 woh[HID];
  __shared__ __align__(16) float g1b[8 * 144];
  __shared__ __align__(16) float g2b[8 * 144];
  __shared__ float xbuf[2][T_LEN];
  __shared__ float outbuf[2][T_LEN];

  const int tid = threadIdx.x;
  const int l   = tid & 63;
  const int w   = tid >> 6;        // wave 0..7
  const int col = l & 15;
  const int q   = l >> 4;
  const int b0  = blockIdx.x * 2;

  // V role
  const int u  = tid >> 2;         // unit 0..127
  const int bb = (tid >> 1) & 1;   // batch
  const int L  = tid & 1;          // 0: layer2, 1: layer1

  // ---- A-fragments into registers/AGPRs (one-time) ----
  f32x4n A1[16], A2[16], AI[16];
#pragma unroll
  for (int f = 0; f < 16; ++f) {
    A1[f] = __builtin_bit_cast(f32x4n, wfrag[((0 * 8 + w) * 16 + f) * 64 + l]);
    A2[f] = __builtin_bit_cast(f32x4n, wfrag[((1 * 8 + w) * 16 + f) * 64 + l]);
    AI[f] = __builtin_bit_cast(f32x4n, wfrag[((2 * 8 + w) * 16 + f) * 64 + l]);
  }
#pragma unroll
  for (int f = 0; f < 16; ++f)
    asm volatile("" : "+v"(A1[f]), "+v"(A2[f]), "+v"(AI[f]));

  // ---- V-role constants ----
  const float* bi = L ? bih1 : bih2;
  const float* bh = L ? bhh1 : bhh2;
  float bc[4], wx[4];
#pragma unroll
  for (int g = 0; g < 4; ++g) {
    bc[g] = bi[g * HID + u] + bh[g * HID + u];
    wx[g] = L ? Wih1[g * HID + u] : 0.f;
  }
  const float bo = bout[0];
  float cst = 0.f;
  float* gb = L ? g1b : g2b;
  _Float16* hdst = (L ? hB1 : hB2) + bb * HB_STR + u;

  // ---- init LDS ----
  if (tid < HID) woh[tid] = (_Float16)Wout[tid];
#pragma unroll
  for (int i = 0; i < 4; ++i) {
    int idx = tid + 512 * i;
    int bq  = idx >> 10;
    int ps  = idx & 1023;
    xbuf[bq][ps] = xin[(size_t)(b0 + bq) * T_LEN + ps];
  }
  __syncthreads();

  // ---- prologue: h1(0) (L=1); zero h2 (L=0) ----
  if (L) {
    float x0 = xbuf[bb][0];
    float v0 = fmaf(wx[0], x0, bc[0]);
    float v2 = fmaf(wx[2], x0, bc[2]);
    float v3 = fmaf(wx[3], x0, bc[3]);
    float si = fsig(v0), tg = ftanh(v2), so = fsig(v3);
    cst = si * tg;                       // f * c0 = 0
    *hdst = (_Float16)(so * ftanh(cst));
  } else {
    *hdst = (_Float16)0.f;
  }
  __syncthreads();

  const int hb    = (col & 1) * HB_STR + q * 8;   // broadcast B base (halves)
  const int sbase = col * 144 + 16 * w + 4 * q;   // scatter base (col<2)

  for (int t = 0; t < T_LEN; ++t) {
    // ================= M: MFMA + scatter + out(t-1) =================
    f16x8 Bh0 = *reinterpret_cast<const f16x8*>(&hB1[hb +  0]);
    f16x8 Bh1 = *reinterpret_cast<const f16x8*>(&hB1[hb + 32]);
    f16x8 Bh2 = *reinterpret_cast<const f16x8*>(&hB1[hb + 64]);
    f16x8 Bh3 = *reinterpret_cast<const f16x8*>(&hB1[hb + 96]);
    f16x8 Dh0 = *reinterpret_cast<const f16x8*>(&hB2[hb +  0]);
    f16x8 Dh1 = *reinterpret_cast<const f16x8*>(&hB2[hb + 32]);
    f16x8 Dh2 = *reinterpret_cast<const f16x8*>(&hB2[hb + 64]);
    f16x8 Dh3 = *reinterpret_cast<const f16x8*>(&hB2[hb + 96]);

    f32x4n C1i = {0,0,0,0}, C1f = {0,0,0,0}, C1g = {0,0,0,0}, C1o = {0,0,0,0};
    f32x4n C2i = {0,0,0,0}, C2f = {0,0,0,0}, C2g = {0,0,0,0}, C2o = {0,0,0,0};

    C1i = MFMA16(A1[ 0], Bh0, C1i); C1i = MFMA16(A1[ 1], Bh1, C1i);
    C1i = MFMA16(A1[ 2], Bh2, C1i); C1i = MFMA16(A1[ 3], Bh3, C1i);
    C1f = MFMA16(A1[ 4], Bh0, C1f); C1f = MFMA16(A1[ 5], Bh1, C1f);
    C1f = MFMA16(A1[ 6], Bh2, C1f); C1f = MFMA16(A1[ 7], Bh3, C1f);
    C1g = MFMA16(A1[ 8], Bh0, C1g); C1g = MFMA16(A1[ 9], Bh1, C1g);
    C1g = MFMA16(A1[10], Bh2, C1g); C1g = MFMA16(A1[11], Bh3, C1g);
    C1o = MFMA16(A1[12], Bh0, C1o); C1o = MFMA16(A1[13], Bh1, C1o);
    C1o = MFMA16(A1[14], Bh2, C1o); C1o = MFMA16(A1[15], Bh3, C1o);

    C2i = MFMA16(A2[ 0], Dh0, C2i); C2i = MFMA16(A2[ 1], Dh1, C2i);
    C2i = MFMA16(A2[ 2], Dh2, C2i); C2i = MFMA16(A2[ 3], Dh3, C2i);
    C2f = MFMA16(A2[ 4], Dh0, C2f); C2f = MFMA16(A2[ 5], Dh1, C2f);
    C2f = MFMA16(A2[ 6], Dh2, C2f); C2f = MFMA16(A2[ 7], Dh3, C2f);
    C2g = MFMA16(A2[ 8], Dh0, C2g); C2g = MFMA16(A2[ 9], Dh1, C2g);
    C2g = MFMA16(A2[10], Dh2, C2g); C2g = MFMA16(A2[11], Dh3, C2g);
    C2o = MFMA16(A2[12], Dh0, C2o); C2o = MFMA16(A2[13], Dh1, C2o);
    C2o = MFMA16(A2[14], Dh2, C2o); C2o = MFMA16(A2[15], Dh3, C2o);

    C2i = MFMA16(AI[ 0], Bh0, C2i); C2i = MFMA16(AI[ 1], Bh1, C2i);
    C2i = MFMA16(AI[ 2], Bh2, C2i); C2i = MFMA16(AI[ 3], Bh3, C2i);
    C2f = MFMA16(AI[ 4], Bh0, C2f); C2f = MFMA16(AI[ 5], Bh1, C2f);
    C2f = MFMA16(AI[ 6], Bh2, C2f); C2f = MFMA16(AI[ 7], Bh3, C2f);
    C2g = MFMA16(AI[ 8], Bh0, C2g); C2g = MFMA16(AI[ 9], Bh1, C2g);
    C2g = MFMA16(AI[10], Bh2, C2g); C2g = MFMA16(AI[11], Bh3, C2g);
    C2o = MFMA16(AI[12], Bh0, C2o); C2o = MFMA16(AI[13], Bh1, C2o);
    C2o = MFMA16(AI[14], Bh2, C2o); C2o = MFMA16(AI[15], Bh3, C2o);

    // out(t-1) = wo . h2(t-1): wave 0, from the Dh fragments it already has
    if (w == 0 && t > 0) {
      f16x8 W0 = *reinterpret_cast<const f16x8*>(&woh[q * 8 +  0]);
      f16x8 W1 = *reinterpret_cast<const f16x8*>(&woh[q * 8 + 32]);
      f16x8 W2 = *reinterpret_cast<const f16x8*>(&woh[q * 8 + 64]);
      f16x8 W3 = *reinterpret_cast<const f16x8*>(&woh[q * 8 + 96]);
      uint4 d0 = __builtin_bit_cast(uint4, Dh0), w0_ = __builtin_bit_cast(uint4, W0);
      uint4 d1 = __builtin_bit_cast(uint4, Dh1), w1_ = __builtin_bit_cast(uint4, W1);
      uint4 d2 = __builtin_bit_cast(uint4, Dh2), w2_ = __builtin_bit_cast(uint4, W2);
      uint4 d3 = __builtin_bit_cast(uint4, Dh3), w3_ = __builtin_bit_cast(uint4, W3);
      float po = 0.f;
      po = fdot2(w0_.x, d0.x, po); po = fdot2(w0_.y, d0.y, po);
      po = fdot2(w0_.z, d0.z, po); po = fdot2(w0_.w, d0.w, po);
      po = fdot2(w1_.x, d1.x, po); po = fdot2(w1_.y, d1.y, po);
      po = fdot2(w1_.z, d1.z, po); po = fdot2(w1_.w, d1.w, po);
      po = fdot2(w2_.x, d2.x, po); po = fdot2(w2_.y, d2.y, po);
      po = fdot2(w2_.z, d2.z, po); po = fdot2(w2_.w, d2.w, po);
      po = fdot2(w3_.x, d3.x, po); po = fdot2(w3_.y, d3.y, po);
      po = fdot2(w3_.z, d3.z, po); po = fdot2(w3_.w, d3.w, po);
      po += __shfl_xor(po, 16, 64);
      po += __shfl_xor(po, 32, 64);
      if (l < 2) outbuf[l][t - 1] = po;
    }

    if (col < 2) {
      *reinterpret_cast<float4*>(&g1b[0 * 288 + sbase]) = __builtin_bit_cast(float4, C1i);
      *reinterpret_cast<float4*>(&g1b[1 * 288 + sbase]) = __builtin_bit_cast(float4, C1f);
      *reinterpret_cast<float4*>(&g1b[2 * 288 + sbase]) = __builtin_bit_cast(float4, C1g);
      *reinterpret_cast<float4*>(&g1b[3 * 288 + sbase]) = __builtin_bit_cast(float4, C1o);
      *reinterpret_cast<float4*>(&g2b[0 * 288 + sbase]) = __builtin_bit_cast(float4, C2i);
      *reinterpret_cast<float4*>(&g2b[1 * 288 + sbase]) = __builtin_bit_cast(float4, C2f);
      *reinterpret_cast<float4*>(&g2b[2 * 288 + sbase]) = __builtin_bit_cast(float4, C2g);
      *reinterpret_cast<float4*>(&g2b[3 * 288 + sbase]) = __builtin_bit_cast(float4, C2o);
    }
    __syncthreads();   // ---- barrier 1 ----

    // ================= V: state updates (no shuffles) =================
    {
      int tn = (t + 1) & (T_LEN - 1);
      float xv = xbuf[bb][tn];           // used only when L==1 (wx==0 else)
      float v0 = gb[0 * 288 + bb * 144 + u] + fmaf(wx[0], xv, bc[0]);
      float v1 = gb[1 * 288 + bb * 144 + u] + fmaf(wx[1], xv, bc[1]);
      float v2 = gb[2 * 288 + bb * 144 + u] + fmaf(wx[2], xv, bc[2]);
      float v3 = gb[3 * 288 + bb * 144 + u] + fmaf(wx[3], xv, bc[3]);
      float si = fsig(v0), sf = fsig(v1), tg = ftanh(v2), so = fsig(v3);
      cst = fmaf(sf, cst, si * tg);
      *hdst = (_Float16)(so * ftanh(cst));
    }
    __syncthreads();   // ---- barrier 2 ----
  }

  // ---- tail: out(T-1) from final h2 ----
  if (w == 0) {
    f16x8 Dh0 = *reinterpret_cast<const f16x8*>(&hB2[hb +  0]);
    f16x8 Dh1 = *reinterpret_cast<const f16x8*>(&hB2[hb + 32]);
    f16x8 Dh2 = *reinterpret_cast<const f16x8*>(&hB2[hb + 64]);
    f16x8 Dh3 = *reinterpret_cast<const f16x8*>(&hB2[hb + 96]);
    f16x8 W0 = *reinterpret_cast<const f16x8*>(&woh[q * 8 +  0]);
    f16x8 W1 = *reinterpret_cast<const f16x8*>(&woh[q * 8 + 32]);
    f16x8 W2 = *reinterpret_cast<const f16x8*>(&woh[q * 8 + 64]);
    f16x8 W3 = *reinterpret_cast<const f16x8*>(&woh[q * 8 + 96]);
    uint4 d0 = __builtin_bit_cast(uint4, Dh0), w0_ = __builtin_bit_cast(uint4, W0);
    uint4 d1 = __builtin_bit_cast(uint4, Dh1), w1_ = __builtin_bit_cast(uint4, W1);
    uint4 d2 = __builtin_bit_cast(uint4, Dh2), w2_ = __builtin_bit_cast(uint4, W2);
    uint4 d3 = __builtin_bit_cast(uint4, Dh3), w3_ = __builtin_bit_cast(uint4, W3);
    float po = 0.f;
    po = fdot2(w0_.x, d0.x, po); po = fdot2(w0_.y, d0.y, po);
    po = fdot2(w0_.z, d0.z, po); po = fdot2(w0_.w, d0.w, po);
    po = fdot2(w1_.x, d1.x, po); po = fdot2(w1_.y, d1.y, po);
    po = fdot2(w1_.z, d1.z, po); po = fdot2(w1_.w, d1.w, po);
    po = fdot2(w2_.x, d2.x, po); po = fdot2(w2_.y, d2.y, po);
    po = fdot2(w2_.z, d2.z, po); po = fdot2(w2_.w, d2.w, po);
    po = fdot2(w3_.x, d3.x, po); po = fdot2(w3_.y, d3.y, po);
    po = fdot2(w3_.z, d3.z, po); po = fdot2(w3_.w, d3.w, po);
    po += __shfl_xor(po, 16, 64);
    po += __shfl_xor(po, 32, 64);
    if (l < 2) outbuf[l][T_LEN - 1] = po;
  }
  __syncthreads();

  // ---- epilogue: coalesced store ----
#pragma unroll
  for (int i = 0; i < 4; ++i) {
    int idx = tid + 512 * i;
    int bq  = idx >> 10;
    int ps  = idx & 1023;
    outp[(size_t)(b0 + bq) * T_LEN + ps] = outbuf[bq][ps] + bo;
  }
}

// ---------------------------------------------------------------------------
// Fallback (round-1, known-correct fp32 path)
// ---------------------------------------------------------------------------
__global__ void __launch_bounds__(512) transpose_w(
    const float* __restrict__ w1, const float* __restrict__ w2,
    const float* __restrict__ w3, float* __restrict__ o) {
  int m = blockIdx.y;
  const float* src = (m == 0) ? w1 : (m == 1) ? w2 : w3;
  float* dst = o + (size_t)m * G4 * HID;
  int idx = blockIdx.x * 512 + threadIdx.x;
  int j = idx >> 7;
  int k = idx & (HID - 1);
  dst[k * G4 + j] = src[idx];
}

__device__ __forceinline__ float gact(float v, int gt) {
  return (gt == 2) ? ftanh(v) : fsig(v);
}

__device__ __forceinline__ void store_out4(const float4* h2buf, float wo0, float wo1,
                                           float bo, int tid, int b0,
                                           float* __restrict__ outp, int t) {
  float4 ha = h2buf[tid];
  float4 hb = h2buf[tid + 64];
  float p0 = wo0 * ha.x + wo1 * hb.x;
  float p1 = wo0 * ha.y + wo1 * hb.y;
  float p2 = wo0 * ha.z + wo1 * hb.z;
  float p3 = wo0 * ha.w + wo1 * hb.w;
#pragma unroll
  for (int off = 1; off < 64; off <<= 1) {
    p0 += __shfl_xor(p0, off, 64);
    p1 += __shfl_xor(p1, off, 64);
    p2 += __shfl_xor(p2, off, 64);
    p3 += __shfl_xor(p3, off, 64);
  }
  if (tid < BCH) {
    float v = (tid == 0) ? p0 : (tid == 1) ? p1 : (tid == 2) ? p2 : p3;
    outp[(size_t)(b0 + tid) * T_LEN + t] = v + bo;
  }
}

__global__ void __launch_bounds__(512) lstm_fused(
    const float* __restrict__ xin, const float* __restrict__ Wih1,
    const float* __restrict__ bih1, const float* __restrict__ bhh1,
    const float* __restrict__ Whh1, const float* __restrict__ Wih2,
    const float* __restrict__ Whh2, int sk, int sj,
    const float* __restrict__ bih2, const float* __restrict__ bhh2,
    const float* __restrict__ Wout, const float* __restrict__ bout,
    float* __restrict__ outp) {
  __shared__ float4 h1buf[HID];
  __shared__ float4 h2buf[HID];
  __shared__ float4 g1[G4];
  __shared__ float4 g2[G4];
  __shared__ float xb[2][BCH];

  const int tid = threadIdx.x;
  const int b0 = blockIdx.x * BCH;
  const int gt = tid >> 7;

  float bias1 = bih1[tid] + bhh1[tid];
  float bias2 = bih2[tid] + bhh2[tid];
  float wi1 = Wih1[tid];
  float c1_0 = 0.f, c1_1 = 0.f, c1_2 = 0.f, c1_3 = 0.f;
  float c2_0 = 0.f, c2_1 = 0.f, c2_2 = 0.f, c2_3 = 0.f;
  float wo0 = 0.f, wo1 = 0.f, bo = 0.f;
  if (tid < 64) { wo0 = Wout[tid]; wo1 = Wout[tid + 64]; bo = bout[0]; }
  if (tid < HID) {
    h1buf[tid] = make_float4(0.f, 0.f, 0.f, 0.f);
    h2buf[tid] = make_float4(0.f, 0.f, 0.f, 0.f);
  }
  if (tid < BCH) xb[0][tid] = xin[(b0 + tid) * T_LEN];
  __syncthreads();

  const float* wp1  = Whh1 + tid * sj;
  const float* wp2  = Whh2 + tid * sj;
  const float* wpi2 = Wih2 + tid * sj;

  for (int t = 0; t < T_LEN; ++t) {
    float xpref = 0.f;
    if ((tid & ~3) == 128 && (t + 1) < T_LEN)
      xpref = xin[(b0 + (tid & 3)) * T_LEN + t + 1];

    if (tid < 64 && t > 0) store_out4(h2buf, wo0, wo1, bo, tid, b0, outp, t - 1);

    float xv0 = xb[t & 1][0], xv1 = xb[t & 1][1];
    float xv2 = xb[t & 1][2], xv3 = xb[t & 1][3];
    float a10 = fmaf(wi1, xv0, bias1);
    float a11 = fmaf(wi1, xv1, bias1);
    float a12 = fmaf(wi1, xv2, bias1);
    float a13 = fmaf(wi1, xv3, bias1);
    float a20 = bias2, a21 = bias2, a22 = bias2, a23 = bias2;
#pragma unroll 8
    for (int k = 0; k < HID; ++k) {
      float w1 = wp1[k * sk];
      float w2 = wp2[k * sk];
      float4 hv1 = h1buf[k];
      float4 hv2 = h2buf[k];
      a10 = fmaf(w1, hv1.x, a10);
      a11 = fmaf(w1, hv1.y, a11);
      a12 = fmaf(w1, hv1.z, a12);
      a13 = fmaf(w1, hv1.w, a13);
      a20 = fmaf(w2, hv2.x, a20);
      a21 = fmaf(w2, hv2.y, a21);
      a22 = fmaf(w2, hv2.z, a22);
      a23 = fmaf(w2, hv2.w, a23);
    }
    float4 A1v;
    A1v.x = gact(a10, gt); A1v.y = gact(a11, gt);
    A1v.z = gact(a12, gt); A1v.w = gact(a13, gt);
    g1[tid] = A1v;
    __syncthreads();

    if (tid < HID) {
      float4 iv = g1[tid], fv = g1[tid + HID];
      float4 gv = g1[tid + 2 * HID], ov = g1[tid + 3 * HID];
      c1_0 = fmaf(fv.x, c1_0, iv.x * gv.x);
      c1_1 = fmaf(fv.y, c1_1, iv.y * gv.y);
      c1_2 = fmaf(fv.z, c1_2, iv.z * gv.z);
      c1_3 = fmaf(fv.w, c1_3, iv.w * gv.w);
      float4 h;
      h.x = ov.x * ftanh(c1_0);
      h.y = ov.y * ftanh(c1_1);
      h.z = ov.z * ftanh(c1_2);
      h.w = ov.w * ftanh(c1_3);
      h1buf[tid] = h;
    }
    __syncthreads();

#pragma unroll 8
    for (int k = 0; k < HID; ++k) {
      float wv = wpi2[k * sk];
      float4 hv = h1buf[k];
      a20 = fmaf(wv, hv.x, a20);
      a21 = fmaf(wv, hv.y, a21);
      a22 = fmaf(wv, hv.z, a22);
      a23 = fmaf(wv, hv.w, a23);
    }
    float4 A2v;
    A2v.x = gact(a20, gt); A2v.y = gact(a21, gt);
    A2v.z = gact(a22, gt); A2v.w = gact(a23, gt);
    g2[tid] = A2v;
    __syncthreads();

    if (tid < HID) {
      float4 iv = g2[tid], fv = g2[tid + HID];
      float4 gv = g2[tid + 2 * HID], ov = g2[tid + 3 * HID];
      c2_0 = fmaf(fv.x, c2_0, iv.x * gv.x);
      c2_1 = fmaf(fv.y, c2_1, iv.y * gv.y);
      c2_2 = fmaf(fv.z, c2_2, iv.z * gv.z);
      c2_3 = fmaf(fv.w, c2_3, iv.w * gv.w);
      float4 h;
      h.x = ov.x * ftanh(c2_0);
      h.y = ov.y * ftanh(c2_1);
      h.z = ov.z * ftanh(c2_2);
      h.w = ov.w * ftanh(c2_3);
      h2buf[tid] = h;
    } else if ((tid & ~3) == 128 && (t + 1) < T_LEN) {
      xb[(t + 1) & 1][tid & 3] = xpref;
    }
    __syncthreads();
  }
  if (tid < 64) store_out4(h2buf, wo0, wo1, bo, tid, b0, outp, T_LEN - 1);
}

extern "C" void kernel_launch(void* const* d_in, const int* in_sizes, int n_in,
                              void* d_out, int out_size, void* d_ws, size_t ws_size,
                              hipStream_t stream) {
  const float* xin  = (const float*)d_in[0];
  const float* Wih1 = (const float*)d_in[1];
  const float* Whh1 = (const float*)d_in[2];
  const float* bih1 = (const float*)d_in[3];
  const float* bhh1 = (const float*)d_in[4];
  const float* Wih2 = (const float*)d_in[5];
  const float* Whh2 = (const float*)d_in[6];
  const float* bih2 = (const float*)d_in[7];
  const float* bhh2 = (const float*)d_in[8];
  const float* Wout = (const float*)d_in[9];
  const float* bout = (const float*)d_in[10];
  float* outp = (float*)d_out;

  const size_t needFr = (size_t)3 * 8 * 16 * 64 * sizeof(uint4);  // 384 KB
  if (ws_size >= needFr) {
    uint4* wfrag = (uint4*)d_ws;
    pack_frag2<<<96, 256, 0, stream>>>(Whh1, Whh2, Wih2, wfrag);
    lstm_v10<<<256, 512, 0, stream>>>(
        xin, Wih1, bih1, bhh1, wfrag, bih2, bhh2, Wout, bout, outp);
    return;
  }

  // fallback: round-1 fp32 kernel
  size_t need = (size_t)3 * G4 * HID * sizeof(float);
  if (ws_size >= need) {
    float* wt = (float*)d_ws;
    transpose_w<<<dim3(128, 3), 512, 0, stream>>>(Whh1, Wih2, Whh2, wt);
    lstm_fused<<<NG, 512, 0, stream>>>(
        xin, Wih1, bih1, bhh1,
        wt, wt + (size_t)G4 * HID, wt + (size_t)2 * G4 * HID, G4, 1,
        bih2, bhh2, Wout, bout, outp);
  } else {
    lstm_fused<<<NG, 512, 0, stream>>>(
        xin, Wih1, bih1, bhh1,
        Whh1, Wih2, Whh2, 1, HID,
        bih2, bhh2, Wout, bout, outp);
  }
}